// Round 8
// baseline (19236.513 us; speedup 1.0000x reference)
//
#include <hip/hip_runtime.h>

// Problem constants: T=128, B=64, D=1024, H=1024. fp32 throughout (the
// recurrence is chaotic: per-step gate noise amplifies ~1e3x over 128 steps;
// fp32 order-noise lands at ~4e-3 absmax, bf16 would fail the 2e-2 gate).
#define TT 128
#define BB 64
#define DD 1024
#define HH 1024
#define G4 4096          // 4*H
#define MM (TT*BB)       // 8192 rows of X flattened
#define BH (BB*HH)       // 65536, one timestep of h/out

#define NWG 256          // persistent grid: exactly 1 block per CU

__device__ __forceinline__ float hsig(float x) {
    x += 0.5f;
    return fminf(fmaxf(x, 0.0f), 1.0f);
}
__device__ __forceinline__ float htanh(float x) {
    return fminf(fmaxf(x, -1.0f), 1.0f);
}

// 4-way in-quad reduction via DPP quad_perm (VALU pipe, no LDS):
// after this, every lane holds the sum over its quad (lane bits 0-1).
__device__ __forceinline__ float quad_sum(float v) {
    union { float f; int i; } u, r;
    u.f = v;
    r.i = __builtin_amdgcn_update_dpp(0, u.i, 0xB1, 0xF, 0xF, true); // [1,0,3,2]
    float v1 = v + r.f;
    u.f = v1;
    r.i = __builtin_amdgcn_update_dpp(0, u.i, 0x4E, 0xF, 0xF, true); // [2,3,0,1]
    return v1 + r.f;
}

// ---------------------------------------------------------------------------
__global__ void zero_bar(unsigned* p) {
    p[threadIdx.x] = 0u;   // flags[256]
}

// ---------------------------------------------------------------------------
// Gx[8192][4096] = X[8192][1024] @ Wx[1024][4096] + bias  (proven, ~700-810 us)
__global__ __launch_bounds__(256) void gx_gemm(const float* __restrict__ X,
                                               const float* __restrict__ W,
                                               const float* __restrict__ bias,
                                               float* __restrict__ C) {
    __shared__ float As[16][132];
    __shared__ float Bs[16][132];

    const int tid = threadIdx.x;
    const int tx = tid & 15;
    const int ty = tid >> 4;
    const int m0 = blockIdx.y * 128;
    const int n0 = blockIdx.x * 128;

    float acc[8][8] = {};
    float4 ra[2], rb[2];

    #pragma unroll
    for (int i = 0; i < 2; ++i) {
        int f4 = tid + i * 256;
        ra[i] = *(const float4*)(X + (size_t)(m0 + (f4 >> 2)) * DD + (f4 & 3) * 4);
        rb[i] = *(const float4*)(W + (size_t)(f4 >> 5) * G4 + n0 + (f4 & 31) * 4);
    }

    for (int k0 = 0; k0 < DD; k0 += 16) {
        #pragma unroll
        for (int i = 0; i < 2; ++i) {
            int f4 = tid + i * 256;
            int mi = f4 >> 2, kq = f4 & 3;
            As[kq * 4 + 0][mi] = ra[i].x;
            As[kq * 4 + 1][mi] = ra[i].y;
            As[kq * 4 + 2][mi] = ra[i].z;
            As[kq * 4 + 3][mi] = ra[i].w;
            *(float4*)&Bs[f4 >> 5][(f4 & 31) * 4] = rb[i];
        }
        __syncthreads();

        const int kn = (k0 + 16 < DD) ? (k0 + 16) : k0;
        #pragma unroll
        for (int i = 0; i < 2; ++i) {
            int f4 = tid + i * 256;
            ra[i] = *(const float4*)(X + (size_t)(m0 + (f4 >> 2)) * DD + kn + (f4 & 3) * 4);
            rb[i] = *(const float4*)(W + (size_t)(kn + (f4 >> 5)) * G4 + n0 + (f4 & 31) * 4);
        }

        #pragma unroll
        for (int kk = 0; kk < 16; ++kk) {
            float ar[8], br[8];
            *(float4*)&ar[0] = *(const float4*)&As[kk][ty * 4];
            *(float4*)&ar[4] = *(const float4*)&As[kk][64 + ty * 4];
            *(float4*)&br[0] = *(const float4*)&Bs[kk][tx * 4];
            *(float4*)&br[4] = *(const float4*)&Bs[kk][64 + tx * 4];
            #pragma unroll
            for (int i = 0; i < 8; ++i)
                #pragma unroll
                for (int j = 0; j < 8; ++j)
                    acc[i][j] += ar[i] * br[j];
        }
        __syncthreads();
    }

    float bl[8];
    *(float4*)&bl[0] = *(const float4*)(bias + n0 + tx * 4);
    *(float4*)&bl[4] = *(const float4*)(bias + n0 + 64 + tx * 4);
    #pragma unroll
    for (int i = 0; i < 8; ++i) {
        int mrow = m0 + ty * 4 + (i & 3) + 64 * (i >> 2);
        float* crow = C + (size_t)mrow * G4 + n0;
        float4 o1, o2;
        o1.x = acc[i][0] + bl[0]; o1.y = acc[i][1] + bl[1];
        o1.z = acc[i][2] + bl[2]; o1.w = acc[i][3] + bl[3];
        o2.x = acc[i][4] + bl[4]; o2.y = acc[i][5] + bl[5];
        o2.z = acc[i][6] + bl[6]; o2.w = acc[i][7] + bl[7];
        *(float4*)(crow + tx * 4) = o1;
        *(float4*)(crow + 64 + tx * 4) = o2;
    }
}

// ---------------------------------------------------------------------------
// Persistent recurrence, fence-free (h crosses wgs as sc0/sc1 agent atomics;
// no __threadfence in the loop -> Wh stays L1/L2-cached the whole kernel).
//
// Grid 256 wgs x 512 thr. wg = btile(4: 16 b) x hct(64: 16 hc); wg owns
// cells (16 b x 16 hc x 4 gates); c lives in a register all 128 steps.
// Thread lanes: wv = tid>>6 (wave), kcs = tid&3 (quad), bh = (tid>>5)&1,
// tt = (tid>>2)&7 -> gate = tt>>1, oct = tt&1. kc = wv*4 + kcs (32 k-chunks
// of 32). Thread tile: 8 b x 8 gc, K-chunk 32.
//
// Key structure:
//  * hs is WAVE-PRIVATE (wave stages its own 16b x 128k slice) -> staging
//    needs only s_waitcnt lgkmcnt(0), no barrier; waves pipeline freely.
//  * kcs 4-way reduced in-register by DPP quad_perm; each quad lane writes
//    a disjoint 16-value slice -> LDS reduce traffic cut 4x.
//  * The two bh half-lanes of an instruction read identical Wh addresses
//    (same cache line, one L2 request).
//  * Only 2 __syncthreads per step (red write->read, read-done->flag).
__global__ __launch_bounds__(512, 1) void lstm_persist(const float* __restrict__ Gx,
                                                       const float* __restrict__ Wh,
                                                       float* __restrict__ out,
                                                       unsigned* __restrict__ flags) {
    __shared__ float hs[8 * 2304];    // per-wave: 16 rows x [4 kcs x 36] (72 KB)
    __shared__ float red[8 * 16 * 68];// [wv][b'][68: gate*17 + hc]   (34.8 KB)

    const int tid  = threadIdx.x;
    const int lane = tid & 63;
    const int wv   = tid >> 6;            // 0..7
    const int kcs  = tid & 3;             // 0..3 (quad position)
    const int bhtt = (tid >> 2) & 15;
    const int bh   = bhtt >> 3;           // 0..1 (b half)
    const int tt   = bhtt & 7;
    const int gate = tt >> 1;             // 0..3
    const int oct  = tt & 1;              // 0..1 (8-hc octet)
    const int kc   = wv * 4 + kcs;        // 0..31

    const int btile = blockIdx.x >> 6;    // 0..3
    const int hct   = blockIdx.x & 63;    // 0..63
    const int b0 = btile * 16;

    const int gc0 = gate * HH + hct * 16 + oct * 8;
    const float* wp = Wh + (size_t)kc * 32 * G4 + gc0;
    float* hsw = &hs[wv * 2304];                     // wave-private region
    const float* hsp = hsw + bh * 1152 + kcs * 36;   // this thread's b-half

    // cell identity (threads 0..255): c in creg all steps
    const bool cell_act = (tid < 256);
    const int b_l  = tid >> 4;            // 0..15
    const int hc_l = tid & 15;            // 0..15
    const size_t cell_g = (size_t)(b0 + b_l) * G4 + hct * 16 + hc_l;
    const size_t cell_h = (size_t)(b0 + b_l) * HH + hct * 16 + hc_l;
    float creg = 0.0f;

    unsigned* gflags = flags + btile * 64;

    // ---- t = 0: gates = Gx[0] (h0 = c0 = 0); publish h(0) through IC
    if (cell_act) {
        const float* gr = Gx + cell_g;
        float ii = hsig(gr[0]);
        float gv = htanh(gr[2 * HH]);
        float oo = hsig(gr[3 * HH]);
        creg = ii * gv;
        __hip_atomic_store(out + cell_h, oo * htanh(creg),
                           __ATOMIC_RELAXED, __HIP_MEMORY_SCOPE_AGENT);
    }
    asm volatile("s_waitcnt vmcnt(0)" ::: "memory");
    __syncthreads();
    if (tid == 0)
        __hip_atomic_store(gflags + hct, 1u, __ATOMIC_RELAXED,
                           __HIP_MEMORY_SCOPE_AGENT);

    for (int t = 1; t < TT; ++t) {
        // prefetch this step's Gx gate values (plain cached loads, own data)
        float gi = 0.f, gf = 0.f, gg = 0.f, go = 0.f;
        if (cell_act) {
            const float* gr = Gx + (size_t)t * BB * G4 + cell_g;
            gi = gr[0];
            gf = gr[HH];
            gg = gr[2 * HH];
            go = gr[3 * HH];
        }

        // ---- per-wave poll: all 64 producers of this btile published h(t-1)
        for (;;) {
            unsigned f = __hip_atomic_load(gflags + lane, __ATOMIC_RELAXED,
                                           __HIP_MEMORY_SCOPE_AGENT);
            if (__all(f >= (unsigned)t)) break;
            __builtin_amdgcn_s_sleep(1);
        }

        // ---- wave-autonomous staging: 16 b x 128 k slice -> hs (own region)
        const float* hprev = out + (size_t)(t - 1) * BH;
        #pragma unroll
        for (int j = 0; j < 16; ++j) {
            const int bi = j;                 // row (uniform per j)
            const int kq = lane;              // ull index within row
            unsigned long long u = __hip_atomic_load(
                (const unsigned long long*)(hprev + (size_t)(b0 + bi) * HH
                                            + wv * 128 + kq * 2),
                __ATOMIC_RELAXED, __HIP_MEMORY_SCOPE_AGENT);
            union { unsigned long long u; float f[2]; } cv;
            cv.u = u;
            float* d = &hsw[bi * 144 + (kq >> 4) * 36 + (kq & 15) * 2];
            d[0] = cv.f[0];
            d[1] = cv.f[1];
        }
        asm volatile("s_waitcnt lgkmcnt(0)" ::: "memory");  // wave-local LDS drain

        // ---- FMA: acc[8 b][8 gc] over k in [kc*32, kc*32+32)
        float acc[8][8] = {};
        #pragma unroll
        for (int k4 = 0; k4 < 8; ++k4) {
            float4 hv[8];
            #pragma unroll
            for (int bi = 0; bi < 8; ++bi)
                hv[bi] = *(const float4*)(hsp + bi * 144 + k4 * 4);
            #pragma unroll
            for (int kk = 0; kk < 4; ++kk) {
                const float* wk = wp + (size_t)(k4 * 4 + kk) * G4;
                float4 w0 = *(const float4*)(wk);
                float4 w1 = *(const float4*)(wk + 4);
                #pragma unroll
                for (int bi = 0; bi < 8; ++bi) {
                    float h = (kk == 0) ? hv[bi].x : (kk == 1) ? hv[bi].y
                              : (kk == 2) ? hv[bi].z : hv[bi].w;
                    acc[bi][0] += h * w0.x;
                    acc[bi][1] += h * w0.y;
                    acc[bi][2] += h * w0.z;
                    acc[bi][3] += h * w0.w;
                    acc[bi][4] += h * w1.x;
                    acc[bi][5] += h * w1.y;
                    acc[bi][6] += h * w1.z;
                    acc[bi][7] += h * w1.w;
                }
            }
        }

        // ---- DPP quad butterfly: sum the 4 kcs of each quad in-register
        #pragma unroll
        for (int bi = 0; bi < 8; ++bi)
            #pragma unroll
            for (int j = 0; j < 8; ++j)
                acc[bi][j] = quad_sum(acc[bi][j]);

        // ---- redistribute-write: quad lane kcs writes acc slice kcs*16..+15
        // red row = wv*16 + b'; col = gate*17 + oct*8 + jj (skewed, <68)
        #pragma unroll
        for (int j2 = 0; j2 < 16; ++j2) {
            int a  = kcs * 16 + j2;
            int bi = a >> 3;
            int jj = a & 7;
            red[(wv * 16 + bh * 8 + bi) * 68 + gate * 17 + oct * 8 + jj] =
                acc[bi][jj];
        }
        __syncthreads();                   // all wave partials visible

        // ---- cell: sum 8 wave-partials x 4 gates; update c; publish h
        if (cell_act) {
            float g4v[4];
            #pragma unroll
            for (int g = 0; g < 4; ++g) {
                float s = 0.0f;
                #pragma unroll
                for (int w2 = 0; w2 < 8; ++w2)
                    s += red[(w2 * 16 + b_l) * 68 + g * 17 + hc_l];
                g4v[g] = s;
            }
            float ii = hsig(gi + g4v[0]);
            float ff = hsig(gf + g4v[1]);
            float gv = htanh(gg + g4v[2]);
            float oo = hsig(go + g4v[3]);
            creg = ff * creg + ii * gv;
            __hip_atomic_store(out + (size_t)t * BH + cell_h, oo * htanh(creg),
                               __ATOMIC_RELAXED, __HIP_MEMORY_SCOPE_AGENT);
        }
        asm volatile("s_waitcnt vmcnt(0)" ::: "memory");
        __syncthreads();                   // publishes acked; red reads done
        if (tid == 0)
            __hip_atomic_store(gflags + hct, (unsigned)(t + 1),
                               __ATOMIC_RELAXED, __HIP_MEMORY_SCOPE_AGENT);
    }
}

// ---------------------------------------------------------------------------
extern "C" void kernel_launch(void* const* d_in, const int* in_sizes, int n_in,
                              void* d_out, int out_size, void* d_ws, size_t ws_size,
                              hipStream_t stream) {
    const float* x  = (const float*)d_in[0];   // [T,B,D]
    const float* Wx = (const float*)d_in[1];   // [D,4H]
    const float* Wh = (const float*)d_in[2];   // [H,4H]
    const float* bs = (const float*)d_in[3];   // [4H]
    float* out = (float*)d_out;                // [T,B,H] — doubles as h history

    // ws layout (floats): Gx 33,554,432 | flags (256 u32)
    float* Gx = (float*)d_ws;
    unsigned* flags = (unsigned*)(Gx + (size_t)MM * G4);

    zero_bar<<<dim3(1), dim3(256), 0, stream>>>(flags);

    // Gx = X @ Wx + b for all timesteps at once
    gx_gemm<<<dim3(G4 / 128, MM / 128), dim3(256), 0, stream>>>(x, Wx, bs, Gx);

    // all 128 recurrent steps in one plain-launch persistent kernel
    lstm_persist<<<dim3(NWG), dim3(512), 0, stream>>>(Gx, Wh, out, flags);
}

// Round 9
// 4123.895 us; speedup vs baseline: 4.6646x; 4.6646x over previous
//
#include <hip/hip_runtime.h>

// Problem constants: T=128, B=64, D=1024, H=1024. fp32 throughout (the
// recurrence is chaotic: per-step gate noise amplifies ~1e3x over 128 steps;
// fp32 order-noise lands at ~4e-3 absmax, bf16 would fail the 2e-2 gate).
#define TT 128
#define BB 64
#define DD 1024
#define HH 1024
#define G4 4096          // 4*H
#define MM (TT*BB)       // 8192 rows of X flattened
#define BH (BB*HH)       // 65536, one timestep of h/out

#define NWG 256          // persistent grid: exactly 1 block per CU

__device__ __forceinline__ float hsig(float x) {
    x += 0.5f;
    return fminf(fmaxf(x, 0.0f), 1.0f);
}
__device__ __forceinline__ float htanh(float x) {
    return fminf(fmaxf(x, -1.0f), 1.0f);
}

// 4-way in-quad reduction via DPP quad_perm (VALU pipe, no LDS):
// after this, every lane holds the sum over its quad (lane bits 0-1).
__device__ __forceinline__ float quad_sum(float v) {
    union { float f; int i; } u, r;
    u.f = v;
    r.i = __builtin_amdgcn_update_dpp(0, u.i, 0xB1, 0xF, 0xF, true); // [1,0,3,2]
    float v1 = v + r.f;
    u.f = v1;
    r.i = __builtin_amdgcn_update_dpp(0, u.i, 0x4E, 0xF, 0xF, true); // [2,3,0,1]
    return v1 + r.f;
}

// ---------------------------------------------------------------------------
__global__ void zero_bar(unsigned* p) {
    p[threadIdx.x] = 0u;   // flags[256]
}

// ---------------------------------------------------------------------------
// Gx[8192][4096] = X[8192][1024] @ Wx[1024][4096] + bias  (proven, ~810 us)
__global__ __launch_bounds__(256) void gx_gemm(const float* __restrict__ X,
                                               const float* __restrict__ W,
                                               const float* __restrict__ bias,
                                               float* __restrict__ C) {
    __shared__ float As[16][132];
    __shared__ float Bs[16][132];

    const int tid = threadIdx.x;
    const int tx = tid & 15;
    const int ty = tid >> 4;
    const int m0 = blockIdx.y * 128;
    const int n0 = blockIdx.x * 128;

    float acc[8][8] = {};
    float4 ra[2], rb[2];

    #pragma unroll
    for (int i = 0; i < 2; ++i) {
        int f4 = tid + i * 256;
        ra[i] = *(const float4*)(X + (size_t)(m0 + (f4 >> 2)) * DD + (f4 & 3) * 4);
        rb[i] = *(const float4*)(W + (size_t)(f4 >> 5) * G4 + n0 + (f4 & 31) * 4);
    }

    for (int k0 = 0; k0 < DD; k0 += 16) {
        #pragma unroll
        for (int i = 0; i < 2; ++i) {
            int f4 = tid + i * 256;
            int mi = f4 >> 2, kq = f4 & 3;
            As[kq * 4 + 0][mi] = ra[i].x;
            As[kq * 4 + 1][mi] = ra[i].y;
            As[kq * 4 + 2][mi] = ra[i].z;
            As[kq * 4 + 3][mi] = ra[i].w;
            *(float4*)&Bs[f4 >> 5][(f4 & 31) * 4] = rb[i];
        }
        __syncthreads();

        const int kn = (k0 + 16 < DD) ? (k0 + 16) : k0;
        #pragma unroll
        for (int i = 0; i < 2; ++i) {
            int f4 = tid + i * 256;
            ra[i] = *(const float4*)(X + (size_t)(m0 + (f4 >> 2)) * DD + kn + (f4 & 3) * 4);
            rb[i] = *(const float4*)(W + (size_t)(kn + (f4 >> 5)) * G4 + n0 + (f4 & 31) * 4);
        }

        #pragma unroll
        for (int kk = 0; kk < 16; ++kk) {
            float ar[8], br[8];
            *(float4*)&ar[0] = *(const float4*)&As[kk][ty * 4];
            *(float4*)&ar[4] = *(const float4*)&As[kk][64 + ty * 4];
            *(float4*)&br[0] = *(const float4*)&Bs[kk][tx * 4];
            *(float4*)&br[4] = *(const float4*)&Bs[kk][64 + tx * 4];
            #pragma unroll
            for (int i = 0; i < 8; ++i)
                #pragma unroll
                for (int j = 0; j < 8; ++j)
                    acc[i][j] += ar[i] * br[j];
        }
        __syncthreads();
    }

    float bl[8];
    *(float4*)&bl[0] = *(const float4*)(bias + n0 + tx * 4);
    *(float4*)&bl[4] = *(const float4*)(bias + n0 + 64 + tx * 4);
    #pragma unroll
    for (int i = 0; i < 8; ++i) {
        int mrow = m0 + ty * 4 + (i & 3) + 64 * (i >> 2);
        float* crow = C + (size_t)mrow * G4 + n0;
        float4 o1, o2;
        o1.x = acc[i][0] + bl[0]; o1.y = acc[i][1] + bl[1];
        o1.z = acc[i][2] + bl[2]; o1.w = acc[i][3] + bl[3];
        o2.x = acc[i][4] + bl[4]; o2.y = acc[i][5] + bl[5];
        o2.z = acc[i][6] + bl[6]; o2.w = acc[i][7] + bl[7];
        *(float4*)(crow + tx * 4) = o1;
        *(float4*)(crow + 64 + tx * 4) = o2;
    }
}

// ---------------------------------------------------------------------------
// Persistent recurrence, fence-free (h crosses wgs as sc0/sc1 agent atomics;
// no __threadfence in the loop -> Wh stays L1/L2-cached the whole kernel).
//
// Grid 256 wgs x 512 thr. wg = btile(4: 16 b) x hct(64: 16 hc); wg owns
// cells (16 b x 16 hc x 4 gates); c lives in a register all 128 steps.
// Thread lanes: wv = tid>>6 (wave), kcs = tid&3 (quad), bh = (tid>>5)&1,
// gate/oct from tid bits 2..5. kc = wv*4 + kcs. Thread tile: 8 b x 8 gc.
//
//  * hs is WAVE-PRIVATE (wave stages its own 16b x 128k slice) -> staging
//    needs only s_waitcnt lgkmcnt(0), no barrier; waves pipeline freely.
//  * kcs 4-way reduced in-register by DPP quad_perm; lane kcs then writes
//    rows {2kcs, 2kcs+1} with COMPILE-TIME acc indices (4-way predicated
//    branch). NO dynamic indexing into register arrays: round 8's
//    acc[a>>3][a&7] with runtime a demoted acc to scratch -> 75 GB/dispatch
//    of HBM spill traffic, VALUBusy 3%. Static indices keep acc in VGPRs.
//  * Only 2 __syncthreads per step (red write->read, read-done->flag).
__global__ __launch_bounds__(512, 1) void lstm_persist(const float* __restrict__ Gx,
                                                       const float* __restrict__ Wh,
                                                       float* __restrict__ out,
                                                       unsigned* __restrict__ flags) {
    __shared__ float hs[8 * 2304];    // per-wave: 16 rows x [4 kcs x 36] (72 KB)
    __shared__ float red[8 * 16 * 68];// [wv][b'][68: gate*17 + hc]   (34.8 KB)

    const int tid  = threadIdx.x;
    const int lane = tid & 63;
    const int wv   = tid >> 6;            // 0..7
    const int kcs  = tid & 3;             // 0..3 (quad position)
    const int bhtt = (tid >> 2) & 15;
    const int bh   = bhtt >> 3;           // 0..1 (b half)
    const int tt   = bhtt & 7;
    const int gate = tt >> 1;             // 0..3
    const int oct  = tt & 1;              // 0..1 (8-hc octet)
    const int kc   = wv * 4 + kcs;        // 0..31

    const int btile = blockIdx.x >> 6;    // 0..3
    const int hct   = blockIdx.x & 63;    // 0..63
    const int b0 = btile * 16;

    const int gc0 = gate * HH + hct * 16 + oct * 8;
    const float* wp = Wh + (size_t)kc * 32 * G4 + gc0;
    float* hsw = &hs[wv * 2304];                     // wave-private region
    const float* hsp = hsw + bh * 1152 + kcs * 36;   // this thread's b-half

    // cell identity (threads 0..255): c in creg all steps
    const bool cell_act = (tid < 256);
    const int b_l  = tid >> 4;            // 0..15
    const int hc_l = tid & 15;            // 0..15
    const size_t cell_g = (size_t)(b0 + b_l) * G4 + hct * 16 + hc_l;
    const size_t cell_h = (size_t)(b0 + b_l) * HH + hct * 16 + hc_l;
    float creg = 0.0f;

    unsigned* gflags = flags + btile * 64;

    // base pointer for this thread's red writes (row chosen per kcs below)
    float* const redw = &red[(wv * 16 + bh * 8) * 68 + gate * 17 + oct * 8];

    // ---- t = 0: gates = Gx[0] (h0 = c0 = 0); publish h(0) through IC
    if (cell_act) {
        const float* gr = Gx + cell_g;
        float ii = hsig(gr[0]);
        float gv = htanh(gr[2 * HH]);
        float oo = hsig(gr[3 * HH]);
        creg = ii * gv;
        __hip_atomic_store(out + cell_h, oo * htanh(creg),
                           __ATOMIC_RELAXED, __HIP_MEMORY_SCOPE_AGENT);
    }
    asm volatile("s_waitcnt vmcnt(0)" ::: "memory");
    __syncthreads();
    if (tid == 0)
        __hip_atomic_store(gflags + hct, 1u, __ATOMIC_RELAXED,
                           __HIP_MEMORY_SCOPE_AGENT);

    for (int t = 1; t < TT; ++t) {
        // prefetch this step's Gx gate values (plain cached loads, own data)
        float gi = 0.f, gf = 0.f, gg = 0.f, go = 0.f;
        if (cell_act) {
            const float* gr = Gx + (size_t)t * BB * G4 + cell_g;
            gi = gr[0];
            gf = gr[HH];
            gg = gr[2 * HH];
            go = gr[3 * HH];
        }

        // ---- per-wave poll: all 64 producers of this btile published h(t-1)
        for (;;) {
            unsigned f = __hip_atomic_load(gflags + lane, __ATOMIC_RELAXED,
                                           __HIP_MEMORY_SCOPE_AGENT);
            if (__all(f >= (unsigned)t)) break;
            __builtin_amdgcn_s_sleep(1);
        }

        // ---- wave-autonomous staging: 16 b x 128 k slice -> hs (own region)
        const float* hprev = out + (size_t)(t - 1) * BH;
        #pragma unroll
        for (int j = 0; j < 16; ++j) {
            const int bi = j;
            const int kq = lane;
            unsigned long long u = __hip_atomic_load(
                (const unsigned long long*)(hprev + (size_t)(b0 + bi) * HH
                                            + wv * 128 + kq * 2),
                __ATOMIC_RELAXED, __HIP_MEMORY_SCOPE_AGENT);
            union { unsigned long long uu; float f[2]; } cv;
            cv.uu = u;
            float* d = &hsw[bi * 144 + (kq >> 4) * 36 + (kq & 15) * 2];
            d[0] = cv.f[0];
            d[1] = cv.f[1];
        }
        asm volatile("s_waitcnt lgkmcnt(0)" ::: "memory");  // wave-local drain

        // ---- FMA: acc[8 b][8 gc] over k in [kc*32, kc*32+32)
        float acc[8][8] = {};
        #pragma unroll
        for (int k4 = 0; k4 < 8; ++k4) {
            float4 hv[8];
            #pragma unroll
            for (int bi = 0; bi < 8; ++bi)
                hv[bi] = *(const float4*)(hsp + bi * 144 + k4 * 4);
            #pragma unroll
            for (int kk = 0; kk < 4; ++kk) {
                const float* wk = wp + (size_t)(k4 * 4 + kk) * G4;
                float4 w0 = *(const float4*)(wk);
                float4 w1 = *(const float4*)(wk + 4);
                #pragma unroll
                for (int bi = 0; bi < 8; ++bi) {
                    float h = (kk == 0) ? hv[bi].x : (kk == 1) ? hv[bi].y
                              : (kk == 2) ? hv[bi].z : hv[bi].w;
                    acc[bi][0] += h * w0.x;
                    acc[bi][1] += h * w0.y;
                    acc[bi][2] += h * w0.z;
                    acc[bi][3] += h * w0.w;
                    acc[bi][4] += h * w1.x;
                    acc[bi][5] += h * w1.y;
                    acc[bi][6] += h * w1.z;
                    acc[bi][7] += h * w1.w;
                }
            }
        }

        // ---- DPP quad butterfly: sum the 4 kcs of each quad in-register
        #pragma unroll
        for (int bi = 0; bi < 8; ++bi)
            #pragma unroll
            for (int j = 0; j < 8; ++j)
                acc[bi][j] = quad_sum(acc[bi][j]);

        // ---- redistribute-write with STATIC acc indices: lane kcs writes
        // rows {2kcs, 2kcs+1} of its b-half (1/4 exec per branch body).
        #define STORE_ROW(r)                                        \
            {                                                       \
                float* rp = redw + (r) * 68;                        \
                rp[0] = acc[r][0]; rp[1] = acc[r][1];               \
                rp[2] = acc[r][2]; rp[3] = acc[r][3];               \
                rp[4] = acc[r][4]; rp[5] = acc[r][5];               \
                rp[6] = acc[r][6]; rp[7] = acc[r][7];               \
            }
        if (kcs == 0)      { STORE_ROW(0) STORE_ROW(1) }
        else if (kcs == 1) { STORE_ROW(2) STORE_ROW(3) }
        else if (kcs == 2) { STORE_ROW(4) STORE_ROW(5) }
        else               { STORE_ROW(6) STORE_ROW(7) }
        #undef STORE_ROW
        __syncthreads();                   // all wave partials visible

        // ---- cell: sum 8 wave-partials x 4 gates; update c; publish h
        if (cell_act) {
            float g4v[4];
            #pragma unroll
            for (int g = 0; g < 4; ++g) {
                float s = 0.0f;
                #pragma unroll
                for (int w2 = 0; w2 < 8; ++w2)
                    s += red[(w2 * 16 + b_l) * 68 + g * 17 + hc_l];
                g4v[g] = s;
            }
            float ii = hsig(gi + g4v[0]);
            float ff = hsig(gf + g4v[1]);
            float gv = htanh(gg + g4v[2]);
            float oo = hsig(go + g4v[3]);
            creg = ff * creg + ii * gv;
            __hip_atomic_store(out + (size_t)t * BH + cell_h, oo * htanh(creg),
                               __ATOMIC_RELAXED, __HIP_MEMORY_SCOPE_AGENT);
        }
        asm volatile("s_waitcnt vmcnt(0)" ::: "memory");
        __syncthreads();                   // publishes acked; red reads done
        if (tid == 0)
            __hip_atomic_store(gflags + hct, (unsigned)(t + 1),
                               __ATOMIC_RELAXED, __HIP_MEMORY_SCOPE_AGENT);
    }
}

// ---------------------------------------------------------------------------
extern "C" void kernel_launch(void* const* d_in, const int* in_sizes, int n_in,
                              void* d_out, int out_size, void* d_ws, size_t ws_size,
                              hipStream_t stream) {
    const float* x  = (const float*)d_in[0];   // [T,B,D]
    const float* Wx = (const float*)d_in[1];   // [D,4H]
    const float* Wh = (const float*)d_in[2];   // [H,4H]
    const float* bs = (const float*)d_in[3];   // [4H]
    float* out = (float*)d_out;                // [T,B,H] — doubles as h history

    // ws layout (floats): Gx 33,554,432 | flags (256 u32)
    float* Gx = (float*)d_ws;
    unsigned* flags = (unsigned*)(Gx + (size_t)MM * G4);

    zero_bar<<<dim3(1), dim3(256), 0, stream>>>(flags);

    // Gx = X @ Wx + b for all timesteps at once
    gx_gemm<<<dim3(G4 / 128, MM / 128), dim3(256), 0, stream>>>(x, Wx, bs, Gx);

    // all 128 recurrent steps in one plain-launch persistent kernel
    lstm_persist<<<dim3(NWG), dim3(512), 0, stream>>>(Gx, Wh, out, flags);
}

// Round 10
// 3578.603 us; speedup vs baseline: 5.3754x; 1.1524x over previous
//
#include <hip/hip_runtime.h>

// Problem constants: T=128, B=64, D=1024, H=1024. fp32 throughout (the
// recurrence is chaotic: per-step gate noise amplifies ~1e3x over 128 steps;
// fp32 order-noise lands at ~4e-3 absmax, bf16 would fail the 2e-2 gate).
#define TT 128
#define BB 64
#define DD 1024
#define HH 1024
#define G4 4096          // 4*H
#define MM (TT*BB)       // 8192 rows of X flattened
#define BH (BB*HH)       // 65536, one timestep of h/out

#define NWG 256          // persistent grid: exactly 1 block per CU

__device__ __forceinline__ float hsig(float x) {
    x += 0.5f;
    return fminf(fmaxf(x, 0.0f), 1.0f);
}
__device__ __forceinline__ float htanh(float x) {
    return fminf(fmaxf(x, -1.0f), 1.0f);
}

// 4-way in-quad reduction via DPP quad_perm (VALU pipe, no LDS):
// after this, every lane holds the sum over its quad (lane bits 0-1).
__device__ __forceinline__ float quad_sum(float v) {
    union { float f; int i; } u, r;
    u.f = v;
    r.i = __builtin_amdgcn_update_dpp(0, u.i, 0xB1, 0xF, 0xF, true); // [1,0,3,2]
    float v1 = v + r.f;
    u.f = v1;
    r.i = __builtin_amdgcn_update_dpp(0, u.i, 0x4E, 0xF, 0xF, true); // [2,3,0,1]
    return v1 + r.f;
}

// ---------------------------------------------------------------------------
__global__ void zero_bar(unsigned* p) {
    p[threadIdx.x] = 0u;   // flags[256]
}

// ---------------------------------------------------------------------------
// Gx[8192][4096] = X[8192][1024] @ Wx[1024][4096] + bias  (proven, ~810 us)
__global__ __launch_bounds__(256) void gx_gemm(const float* __restrict__ X,
                                               const float* __restrict__ W,
                                               const float* __restrict__ bias,
                                               float* __restrict__ C) {
    __shared__ float As[16][132];
    __shared__ float Bs[16][132];

    const int tid = threadIdx.x;
    const int tx = tid & 15;
    const int ty = tid >> 4;
    const int m0 = blockIdx.y * 128;
    const int n0 = blockIdx.x * 128;

    float acc[8][8] = {};
    float4 ra[2], rb[2];

    #pragma unroll
    for (int i = 0; i < 2; ++i) {
        int f4 = tid + i * 256;
        ra[i] = *(const float4*)(X + (size_t)(m0 + (f4 >> 2)) * DD + (f4 & 3) * 4);
        rb[i] = *(const float4*)(W + (size_t)(f4 >> 5) * G4 + n0 + (f4 & 31) * 4);
    }

    for (int k0 = 0; k0 < DD; k0 += 16) {
        #pragma unroll
        for (int i = 0; i < 2; ++i) {
            int f4 = tid + i * 256;
            int mi = f4 >> 2, kq = f4 & 3;
            As[kq * 4 + 0][mi] = ra[i].x;
            As[kq * 4 + 1][mi] = ra[i].y;
            As[kq * 4 + 2][mi] = ra[i].z;
            As[kq * 4 + 3][mi] = ra[i].w;
            *(float4*)&Bs[f4 >> 5][(f4 & 31) * 4] = rb[i];
        }
        __syncthreads();

        const int kn = (k0 + 16 < DD) ? (k0 + 16) : k0;
        #pragma unroll
        for (int i = 0; i < 2; ++i) {
            int f4 = tid + i * 256;
            ra[i] = *(const float4*)(X + (size_t)(m0 + (f4 >> 2)) * DD + kn + (f4 & 3) * 4);
            rb[i] = *(const float4*)(W + (size_t)(kn + (f4 >> 5)) * G4 + n0 + (f4 & 31) * 4);
        }

        #pragma unroll
        for (int kk = 0; kk < 16; ++kk) {
            float ar[8], br[8];
            *(float4*)&ar[0] = *(const float4*)&As[kk][ty * 4];
            *(float4*)&ar[4] = *(const float4*)&As[kk][64 + ty * 4];
            *(float4*)&br[0] = *(const float4*)&Bs[kk][tx * 4];
            *(float4*)&br[4] = *(const float4*)&Bs[kk][64 + tx * 4];
            #pragma unroll
            for (int i = 0; i < 8; ++i)
                #pragma unroll
                for (int j = 0; j < 8; ++j)
                    acc[i][j] += ar[i] * br[j];
        }
        __syncthreads();
    }

    float bl[8];
    *(float4*)&bl[0] = *(const float4*)(bias + n0 + tx * 4);
    *(float4*)&bl[4] = *(const float4*)(bias + n0 + 64 + tx * 4);
    #pragma unroll
    for (int i = 0; i < 8; ++i) {
        int mrow = m0 + ty * 4 + (i & 3) + 64 * (i >> 2);
        float* crow = C + (size_t)mrow * G4 + n0;
        float4 o1, o2;
        o1.x = acc[i][0] + bl[0]; o1.y = acc[i][1] + bl[1];
        o1.z = acc[i][2] + bl[2]; o1.w = acc[i][3] + bl[3];
        o2.x = acc[i][4] + bl[4]; o2.y = acc[i][5] + bl[5];
        o2.z = acc[i][6] + bl[6]; o2.w = acc[i][7] + bl[7];
        *(float4*)(crow + tx * 4) = o1;
        *(float4*)(crow + 64 + tx * 4) = o2;
    }
}

// ---------------------------------------------------------------------------
// Persistent recurrence. Round-7 proven skeleton (fence-free IC h-exchange,
// wg = btile(8: 8 b) x hct(32: 32 hc), 4-byte dword staging loads, same flag
// scheme) + three surgical changes:
//  1. kc = wv*4 + (lane&3): quads span 4 kc-chunks -> DPP quad_perm
//     pre-reduce (VALU pipe) collapses 32 k-partials to 8 wave-partials.
//     acc indexing stays STATIC (per-m 3-select, no divergence) — r8's
//     dynamic-index scratch demotion must never recur.
//  2. One-shot reduce, red[wv][m][lane]: 16 conflict-free scalar writes per
//     thread, 32 reads per cell thread (<=4-way). Cuts reduce LDS-pipe ~3x.
//  3. Per-wave flag poll + merged phases: 4 __syncthreads/step (was 6).
__global__ __launch_bounds__(512, 1) void lstm_persist(const float* __restrict__ Gx,
                                                       const float* __restrict__ Wh,
                                                       float* __restrict__ out,
                                                       unsigned* __restrict__ flags) {
    // union: hs = [8 b][1152 (32 chunks x 36 skew)] = 9216 floats (36.9 KB)
    //        red = [8 wv][16 m][68: 64 lanes + pad] = 8704 floats (aliased)
    __shared__ float smem[9216];
    float* hs  = smem;
    float* red = smem;

    const int tid  = threadIdx.x;
    const int lane = tid & 63;
    const int wv   = tid >> 6;            // 0..7
    const int kcs  = lane & 3;            // quad position = kc low bits
    const int tt   = lane >> 2;           // 0..15 (gate x hq8)
    const int gate = tt >> 2;             // 0..3
    const int hq8  = (tt & 3) * 8;
    const int kc   = wv * 4 + kcs;        // 0..31 (32-k chunk)

    const int btile = blockIdx.x >> 5;    // 0..7
    const int hct   = blockIdx.x & 31;    // 0..31
    const int b0 = btile * 8;

    const int gc0 = gate * HH + hct * 32 + hq8;
    const float* wp = Wh + (size_t)kc * 32 * G4 + gc0;

    // cell identity (threads 0..255): c in creg all steps  (r7 exact)
    const bool cell_act = (tid < 256);
    const int b_l  = tid >> 5;            // 0..7 local b
    const int hc_l = tid & 31;            // 0..31 local hc
    const size_t cell_g = (size_t)(b0 + b_l) * G4 + hct * 32 + hc_l;
    const size_t cell_h = (size_t)(b0 + b_l) * HH + hct * 32 + hc_l;
    float creg = 0.0f;

    // reader base into red: v* = b_l*8 + (hc_l&7) -> m* = v*>>2, kcs* = v*&3
    const int m_r   = b_l * 2 + ((hc_l & 7) >> 2);
    const int kcs_r = hc_l & 3;
    const int h3    = hc_l >> 3;          // selects tt = g*4 + h3

    unsigned* gflags = flags + btile * 32;

    // ---- t = 0: gates = Gx[0] (h0 = c0 = 0); publish h(0) through IC
    if (cell_act) {
        const float* gr = Gx + cell_g;
        float ii = hsig(gr[0]);
        float gv = htanh(gr[2 * HH]);
        float oo = hsig(gr[3 * HH]);
        creg = ii * gv;
        __hip_atomic_store(out + cell_h, oo * htanh(creg),
                           __ATOMIC_RELAXED, __HIP_MEMORY_SCOPE_AGENT);
    }
    asm volatile("s_waitcnt vmcnt(0)" ::: "memory");
    __syncthreads();
    if (tid == 0)
        __hip_atomic_store(gflags + hct, 1u, __ATOMIC_RELAXED,
                           __HIP_MEMORY_SCOPE_AGENT);

    for (int t = 1; t < TT; ++t) {
        // prefetch this step's Gx gate values (plain cached loads, own data)
        float gi = 0.f, gf = 0.f, gg = 0.f, go = 0.f;
        if (cell_act) {
            const float* gr = Gx + (size_t)t * BB * G4 + cell_g;
            gi = gr[0];
            gf = gr[HH];
            gg = gr[2 * HH];
            go = gr[3 * HH];
        }

        // ---- per-wave poll: all 32 producers of this btile published h(t-1)
        for (;;) {
            unsigned f = __hip_atomic_load(gflags + (lane & 31), __ATOMIC_RELAXED,
                                           __HIP_MEMORY_SCOPE_AGENT);
            if (__all(f >= (unsigned)t)) break;
            __builtin_amdgcn_s_sleep(1);
        }

        // ---- stage h(t-1)[b0..b0+7][:] -> skewed hs  (r7-exact dword loads)
        const float* hprev = out + (size_t)(t - 1) * BH;
        #pragma unroll
        for (int i = 0; i < 16; ++i) {
            int idx = tid + i * 512;       // 0..8191
            int bi = idx >> 10;
            int q  = idx & 1023;
            float v = __hip_atomic_load(hprev + (size_t)(b0 + bi) * HH + q,
                                        __ATOMIC_RELAXED, __HIP_MEMORY_SCOPE_AGENT);
            hs[bi * 1152 + (q >> 5) * 36 + (q & 31)] = v;
        }
        __syncthreads();                   // (1) hs ready

        // ---- FMA: acc[8 b][8 gc] over k in [kc*32, kc*32+32)
        float acc[8][8] = {};
        #pragma unroll 2
        for (int k4 = 0; k4 < 8; ++k4) {
            float4 hv[8];
            #pragma unroll
            for (int bi = 0; bi < 8; ++bi)
                hv[bi] = *(const float4*)&hs[bi * 1152 + kc * 36 + k4 * 4];
            #pragma unroll
            for (int kk = 0; kk < 4; ++kk) {
                const float* wk = wp + (size_t)(k4 * 4 + kk) * G4;
                float4 w0 = *(const float4*)(wk);
                float4 w1 = *(const float4*)(wk + 4);
                #pragma unroll
                for (int bi = 0; bi < 8; ++bi) {
                    float h = (kk == 0) ? hv[bi].x : (kk == 1) ? hv[bi].y
                              : (kk == 2) ? hv[bi].z : hv[bi].w;
                    acc[bi][0] += h * w0.x;
                    acc[bi][1] += h * w0.y;
                    acc[bi][2] += h * w0.z;
                    acc[bi][3] += h * w0.w;
                    acc[bi][4] += h * w1.x;
                    acc[bi][5] += h * w1.y;
                    acc[bi][6] += h * w1.z;
                    acc[bi][7] += h * w1.w;
                }
            }
        }

        // ---- DPP quad butterfly: each quad's 4 kc-partials summed in-reg
        #pragma unroll
        for (int bi = 0; bi < 8; ++bi)
            #pragma unroll
            for (int j = 0; j < 8; ++j)
                acc[bi][j] = quad_sum(acc[bi][j]);

        __syncthreads();                   // (2) hs dead; smem becomes red

        // ---- one-shot red write: lane writes value v = 4m + kcs for each m.
        // STATIC acc indices (selected by uniform-per-lane kcs via cndmask);
        // addr = wv*1088 + m*68 + lane -> consecutive lanes, conflict-free.
        #pragma unroll
        for (int m = 0; m < 16; ++m) {
            float v0 = acc[(4 * m + 0) >> 3][(4 * m + 0) & 7];
            float v1 = acc[(4 * m + 1) >> 3][(4 * m + 1) & 7];
            float v2 = acc[(4 * m + 2) >> 3][(4 * m + 2) & 7];
            float v3 = acc[(4 * m + 3) >> 3][(4 * m + 3) & 7];
            float val = (kcs == 0) ? v0 : (kcs == 1) ? v1 : (kcs == 2) ? v2 : v3;
            red[wv * 1088 + m * 68 + lane] = val;
        }
        __syncthreads();                   // (3) all wave partials visible

        // ---- cell: sum 8 wave-partials per gate; update c; publish h
        if (cell_act) {
            float g4v[4];
            #pragma unroll
            for (int g = 0; g < 4; ++g) {
                const int base = m_r * 68 + 4 * (g * 4 + h3) + kcs_r;
                float s = 0.0f;
                #pragma unroll
                for (int w2 = 0; w2 < 8; ++w2)
                    s += red[w2 * 1088 + base];
                g4v[g] = s;
            }
            float ii = hsig(gi + g4v[0]);
            float ff = hsig(gf + g4v[1]);
            float gv = htanh(gg + g4v[2]);
            float oo = hsig(go + g4v[3]);
            creg = ff * creg + ii * gv;
            __hip_atomic_store(out + (size_t)t * BH + cell_h, oo * htanh(creg),
                               __ATOMIC_RELAXED, __HIP_MEMORY_SCOPE_AGENT);
        }
        asm volatile("s_waitcnt vmcnt(0)" ::: "memory");
        __syncthreads();                   // (4) publishes done; red reads done
        if (tid == 0)
            __hip_atomic_store(gflags + hct, (unsigned)(t + 1),
                               __ATOMIC_RELAXED, __HIP_MEMORY_SCOPE_AGENT);
    }
}

// ---------------------------------------------------------------------------
extern "C" void kernel_launch(void* const* d_in, const int* in_sizes, int n_in,
                              void* d_out, int out_size, void* d_ws, size_t ws_size,
                              hipStream_t stream) {
    const float* x  = (const float*)d_in[0];   // [T,B,D]
    const float* Wx = (const float*)d_in[1];   // [D,4H]
    const float* Wh = (const float*)d_in[2];   // [H,4H]
    const float* bs = (const float*)d_in[3];   // [4H]
    float* out = (float*)d_out;                // [T,B,H] — doubles as h history

    // ws layout (floats): Gx 33,554,432 | flags (256 u32)
    float* Gx = (float*)d_ws;
    unsigned* flags = (unsigned*)(Gx + (size_t)MM * G4);

    zero_bar<<<dim3(1), dim3(256), 0, stream>>>(flags);

    // Gx = X @ Wx + b for all timesteps at once
    gx_gemm<<<dim3(G4 / 128, MM / 128), dim3(256), 0, stream>>>(x, Wx, bs, Gx);

    // all 128 recurrent steps in one plain-launch persistent kernel
    lstm_persist<<<dim3(NWG), dim3(512), 0, stream>>>(Gx, Wh, out, flags);
}